// Round 2
// baseline (1104.704 us; speedup 1.0000x reference)
//
#include <hip/hip_runtime.h>

// LSTM_584115552367 — B=65536, T=50, D=17, SLB=30 (runtime).
// 1 thread / batch element (grid-capped at 1 wave/SIMD -> occupancy fixed).
// Wave-uniform weights read via uniform-address scalar loads from a
// __device__ global (prepared by a tiny setup kernel) instead of LDS
// broadcast ds_read — frees the per-CU LDS pipe that capped VALUBusy at 34%.
// h/c live in registers; LDS only stages the x transpose.
// NOTE: round-0 version used d_ws and the run died — d_ws may be null/undersized;
// statically-allocated __device__ buffer removes that failure mode.

#define Dn 17
#define Gn 68
#define Tn 50

// g_ws layout (float offsets); all float4 rows 16B-aligned
#define WZ_OFF 0      // [34][68]  rows 0..16: A^T (x part), 17..33: B^T (h part)
#define CZ_OFF 2312   // [17][68]  free-running fold: (B + Wlin^T A^T)^T
#define WL_OFF 3468   // [17][20]  Wlin^T rows padded to 20
#define BS_OFF 3808   // [68]      b_ih + b_hh
#define BC_OFF 3876   // [68]      folded phase-2 bias
#define BL_OFF 3944   // [20]      b_lin padded
#define WS_FLOATS 3964

__device__ __align__(16) float g_ws[WS_FLOATS];

__device__ __forceinline__ float sigm_(float v) {
    float e = __expf(-v);
    return __builtin_amdgcn_rcpf(1.0f + e);
}
__device__ __forceinline__ float tanh_(float v) {
    float e = __expf(2.0f * v);
    return 1.0f - 2.0f * __builtin_amdgcn_rcpf(e + 1.0f);
}
__device__ __forceinline__ float getc(const float4 v, int c) {
    return c == 0 ? v.x : c == 1 ? v.y : c == 2 ? v.z : v.w;
}
__device__ __forceinline__ void fma4(float4& a, float b, const float4 w) {
    a.x = __builtin_fmaf(b, w.x, a.x);
    a.y = __builtin_fmaf(b, w.y, a.y);
    a.z = __builtin_fmaf(b, w.z, a.z);
    a.w = __builtin_fmaf(b, w.w, a.w);
}

__global__ void lstm_setup(const float* __restrict__ W_ih, const float* __restrict__ W_hh,
                           const float* __restrict__ b_ih, const float* __restrict__ b_hh,
                           const float* __restrict__ W_lin, const float* __restrict__ b_lin,
                           const float* __restrict__ m_ih, const float* __restrict__ m_hh)
{
    __shared__ float A[Gn * Dn];
    __shared__ float Bm[Gn * Dn];
    const int tid = threadIdx.x;
    for (int i = tid; i < Gn * Dn; i += 256) {
        A[i]  = W_ih[i] * m_ih[i];
        Bm[i] = W_hh[i] * m_hh[i];
    }
    __syncthreads();
    // wz[k][j]: k<17 -> A[j][k]; else B[j][k-17]
    for (int i = tid; i < 2 * Dn * Gn; i += 256) {
        int k = i / Gn, j = i - Gn * k;
        g_ws[WZ_OFF + i] = (k < Dn) ? A[j * Dn + k] : Bm[j * Dn + (k - Dn)];
    }
    // cz[k][j] = B[j][k] + sum_m A[j][m] * Wlin[m][k]
    for (int i = tid; i < Dn * Gn; i += 256) {
        int k = i / Gn, j = i - Gn * k;
        float v = Bm[j * Dn + k];
        for (int m = 0; m < Dn; ++m) v = __builtin_fmaf(A[j * Dn + m], W_lin[m * Dn + k], v);
        g_ws[CZ_OFF + i] = v;
    }
    // wl[k][m] (padded to 20)
    for (int i = tid; i < Dn * 20; i += 256) {
        int k = i / 20, m = i - 20 * k;
        g_ws[WL_OFF + i] = (m < Dn) ? W_lin[m * Dn + k] : 0.0f;
    }
    if (tid < Gn) {
        float bsv = b_ih[tid] + b_hh[tid];
        g_ws[BS_OFF + tid] = bsv;
        float v = bsv;
        for (int m = 0; m < Dn; ++m) v = __builtin_fmaf(A[tid * Dn + m], b_lin[m], v);
        g_ws[BC_OFF + tid] = v;
    }
    if (tid < 20) g_ws[BL_OFF + tid] = (tid < Dn) ? b_lin[tid] : 0.0f;
}

__global__ __launch_bounds__(256, 1)
void lstm_main(const float* __restrict__ x,
               const int* __restrict__ slb_p, float* __restrict__ out)
{
    __shared__ float xbuf[2][256 * Dn];   // double-parity x transpose staging (34 KB)

    const int tid = threadIdx.x;
    const int b0  = blockIdx.x * 256;

    const float* __restrict__ wz = g_ws + WZ_OFF;
    const float* __restrict__ cz = g_ws + CZ_OFF;
    const float* __restrict__ wl = g_ws + WL_OFF;
    const float4* bs4 = (const float4*)(g_ws + BS_OFF);
    const float4* bc4 = (const float4*)(g_ws + BC_OFF);
    const float4* bl4 = (const float4*)(g_ws + BL_OFF);

    // coalesced stage of x(t=0); LDS index f = tid + 256*i maps to (br,d)
    int offx[Dn];
    #pragma unroll
    for (int i = 0; i < Dn; ++i) {
        int f  = tid + 256 * i;
        int br = f / Dn, d = f - Dn * br;
        offx[i] = ((b0 + br) * Tn) * Dn + d;
        xbuf[0][f] = x[offx[i]];
    }
    __syncthreads();

    const int slb = slb_p[0];
    float c[Dn], h[Dn];
    #pragma unroll
    for (int e = 0; e < Dn; ++e) { c[e] = 0.0f; h[e] = 0.0f; }

    // ---- phase 1: teacher-forced ----
    for (int t = 0; t < slb; ++t) {
        const bool pre = (t + 1 < slb);
        float gx[Dn];
        if (pre) {
            #pragma unroll
            for (int i = 0; i < Dn; ++i) gx[i] = x[offx[i] + (t + 1) * Dn];
        }
        float4 acc[Dn];
        #pragma unroll
        for (int j = 0; j < Dn; ++j) acc[j] = bs4[j];

        const float* xr = &xbuf[t & 1][tid * Dn];
        #pragma unroll
        for (int k = 0; k < Dn; ++k) {           // x part: zk per-lane, weights uniform (SGPR)
            float zk = xr[k];
            const float4* w4 = (const float4*)(wz + k * Gn);
            #pragma unroll
            for (int j = 0; j < Dn; ++j) fma4(acc[j], zk, w4[j]);
        }
        #pragma unroll
        for (int k = 0; k < Dn; ++k) {           // h part: h in registers (static index)
            float zk = h[k];
            const float4* w4 = (const float4*)(wz + (Dn + k) * Gn);
            #pragma unroll
            for (int j = 0; j < Dn; ++j) fma4(acc[j], zk, w4[j]);
        }
        #pragma unroll
        for (int e = 0; e < Dn; ++e) {
            float gi = getc(acc[e >> 2], e & 3);
            float gf = getc(acc[(Dn + e) >> 2], (Dn + e) & 3);
            float gg = getc(acc[(2 * Dn + e) >> 2], (2 * Dn + e) & 3);
            float go = getc(acc[(3 * Dn + e) >> 2], (3 * Dn + e) & 3);
            float cv = __builtin_fmaf(sigm_(gf), c[e], sigm_(gi) * tanh_(gg));
            c[e] = cv;
            h[e] = sigm_(go) * tanh_(cv);
        }
        if (pre) {
            const int p = (t + 1) & 1;
            #pragma unroll
            for (int i = 0; i < Dn; ++i) xbuf[p][tid + 256 * i] = gx[i];
        }
        __syncthreads();
    }

    // ---- phase 2: free-running (no LDS, no barriers) ----
    const int nout  = Tn - slb;
    const int obase = (b0 + tid) * nout * Dn;
    for (int tp = 0; tp < nout; ++tp) {
        float4 acc[Dn];
        #pragma unroll
        for (int j = 0; j < Dn; ++j) acc[j] = bc4[j];
        #pragma unroll
        for (int k = 0; k < Dn; ++k) {
            float zk = h[k];
            const float4* w4 = (const float4*)(cz + k * Gn);
            #pragma unroll
            for (int j = 0; j < Dn; ++j) fma4(acc[j], zk, w4[j]);
        }
        #pragma unroll
        for (int e = 0; e < Dn; ++e) {
            float gi = getc(acc[e >> 2], e & 3);
            float gf = getc(acc[(Dn + e) >> 2], (Dn + e) & 3);
            float gg = getc(acc[(2 * Dn + e) >> 2], (2 * Dn + e) & 3);
            float go = getc(acc[(3 * Dn + e) >> 2], (3 * Dn + e) & 3);
            float cv = __builtin_fmaf(sigm_(gf), c[e], sigm_(gi) * tanh_(gg));
            c[e] = cv;
            h[e] = sigm_(go) * tanh_(cv);
        }
        // linear head from registers
        float4 o4[5];
        #pragma unroll
        for (int j = 0; j < 5; ++j) o4[j] = bl4[j];
        #pragma unroll
        for (int k = 0; k < Dn; ++k) {
            const float4* w4 = (const float4*)(wl + k * 20);
            #pragma unroll
            for (int j = 0; j < 5; ++j) fma4(o4[j], h[k], w4[j]);
        }
        float* op = out + obase + tp * Dn;
        #pragma unroll
        for (int m = 0; m < Dn; ++m) op[m] = getc(o4[m >> 2], m & 3);
    }
}

extern "C" void kernel_launch(void* const* d_in, const int* in_sizes, int n_in,
                              void* d_out, int out_size, void* d_ws, size_t ws_size,
                              hipStream_t stream) {
    (void)in_sizes; (void)n_in; (void)ws_size; (void)out_size; (void)d_ws;
    const float* x     = (const float*)d_in[0];
    const float* W_ih  = (const float*)d_in[1];
    const float* W_hh  = (const float*)d_in[2];
    const float* b_ih  = (const float*)d_in[3];
    const float* b_hh  = (const float*)d_in[4];
    const float* W_lin = (const float*)d_in[5];
    const float* b_lin = (const float*)d_in[6];
    const float* m_ih  = (const float*)d_in[7];
    const float* m_hh  = (const float*)d_in[8];
    const int*   slb   = (const int*)d_in[9];
    float* out = (float*)d_out;

    lstm_setup<<<dim3(1), dim3(256), 0, stream>>>(
        W_ih, W_hh, b_ih, b_hh, W_lin, b_lin, m_ih, m_hh);
    lstm_main<<<dim3(256), dim3(256), 0, stream>>>(x, slb, out);
}